// Round 11
// baseline (204.745 us; speedup 1.0000x reference)
//
#include <hip/hip_runtime.h>
#include <cstdint>
#include <cstddef>

#define Bn 16
#define Cn 64
#define Hn 256
#define Wn 256
#define HWn (Hn * Wn)          // 65536
#define TH 8                   // tile rows
#define TW 64                  // tile cols
#define ROWS (TH + 2)          // 10
#define COLS (TW + 2)          // 66
#define NBLK (Bn * (Hn / TH) * (Wn / TW))   // 2048

typedef unsigned long long u64;
typedef u64   u64x2 __attribute__((ext_vector_type(2)));
typedef float f32x2 __attribute__((ext_vector_type(2)));
typedef float f32x4 __attribute__((ext_vector_type(4)));

// ---- kernel C: weight sign bits + per-co params + edge-corr sums -------------
__global__ __launch_bounds__(64) void pack_weights(const float* __restrict__ w,
                                                   const float* __restrict__ b0g,
                                                   const float* __restrict__ pwg,
                                                   const float* __restrict__ b1g,
                                                   u64* __restrict__ wbits,
                                                   float4* __restrict__ par,
                                                   int* __restrict__ corrx) {
    const int co = blockIdx.x;
    const int ci = threadIdx.x;
    const float* wp = w + ((size_t)co * Cn + ci) * 9;
    float v[9];
    float asum = 0.f;
    #pragma unroll
    for (int t = 0; t < 9; ++t) { v[t] = wp[t]; asum += fabsf(v[t]); }
    u64 m[9];
    #pragma unroll
    for (int t = 0; t < 9; ++t) m[t] = __ballot(v[t] > 0.f);
    #pragma unroll
    for (int off = 32; off; off >>= 1) asum += __shfl_xor(asum, off);
    if (ci == 0) {
        int c[9];
        #pragma unroll
        for (int t = 0; t < 9; ++t) {
            wbits[co * 9 + t] = m[t];
            c[t] = 64 - 2 * (int)__popcll(m[t]);
        }
        int* cx = corrx + co * 8;
        cx[0] = c[0] + c[1] + c[2];   // top row pad
        cx[1] = c[6] + c[7] + c[8];   // bottom row pad
        cx[2] = c[0] + c[3] + c[6];   // left col pad
        cx[3] = c[2] + c[5] + c[8];   // right col pad
        cx[4] = c[0]; cx[5] = c[2];   // corner overlaps
        cx[6] = c[6]; cx[7] = c[8];
        par[co] = make_float4(asum * (1.f / (Cn * 9)), b0g[co], pwg[co], b1g[co]);
    }
}

// ---- fused kernel: pack 10x66 bit tile + co-quad streaming conv --------------
__global__ __launch_bounds__(256, 8) void fused(const float* __restrict__ x,
                                                const float* __restrict__ rdk,
                                                const float* __restrict__ rdb,
                                                const u64* __restrict__ wbits,
                                                const float4* __restrict__ par,
                                                const int* __restrict__ corrx,
                                                float* __restrict__ out) {
    __shared__ __align__(16) u64 s_a[ROWS][COLS];   // 5280 B
    __shared__ float2 s_rd[Cn];

    const int tid = threadIdx.x;
    // XCD-chunked bijective swizzle (2048 % 8 == 0)
    const int bid     = blockIdx.x;
    const int logical = (bid & 7) * (NBLK / 8) + (bid >> 3);
    const int n   = logical >> 7;
    const int rem = logical & 127;
    const int h0  = (rem >> 2) * TH;
    const int w0  = (rem & 3) * TW;

    if (tid < Cn) s_rd[tid] = make_float2(rdk[tid], rdb[tid]);
    __syncthreads();

    // -------- phase 1: binarize+pack rows h0-1..h0+8, cols w0-1..w0+64 --------
    const float* xn = x + (size_t)n * Cn * HWn;
    if (tid < 180) {
        if (tid < 160) {                            // interior: aligned f32x4
            const int r = tid >> 4;                 // 0..9
            const int q = tid & 15;                 // quad of pixels
            const int gh = h0 - 1 + r;
            const int gw = w0 + 4 * q;
            u64 b0 = 0, b1 = 0, b2 = 0, b3 = 0;
            if (gh >= 0 && gh < Hn) {
                const float* xp = xn + (size_t)gh * Wn + gw;
                #pragma unroll 8
                for (int ci = 0; ci < Cn; ++ci) {
                    const float2 kb = s_rd[ci];
                    const f32x4 v = *reinterpret_cast<const f32x4*>(xp + (size_t)ci * HWn);
                    const u64 bit = 1ull << ci;
                    if (fmaf(v.x, kb.x, kb.y) > 0.f) b0 |= bit;
                    if (fmaf(v.y, kb.x, kb.y) > 0.f) b1 |= bit;
                    if (fmaf(v.z, kb.x, kb.y) > 0.f) b2 |= bit;
                    if (fmaf(v.w, kb.x, kb.y) > 0.f) b3 |= bit;
                }
            }
            s_a[r][1 + 4 * q] = b0;
            s_a[r][2 + 4 * q] = b1;
            s_a[r][3 + 4 * q] = b2;
            s_a[r][4 + 4 * q] = b3;
        } else {                                    // side halo columns
            const int t2 = tid - 160;
            const int r = t2 >> 1;
            const int side = t2 & 1;
            const int gh = h0 - 1 + r;
            const int gw = side ? (w0 + TW) : (w0 - 1);
            u64 b = 0;
            if (gh >= 0 && gh < Hn && gw >= 0 && gw < Wn) {
                const float* xp = xn + (size_t)gh * Wn + gw;
                #pragma unroll 8
                for (int ci = 0; ci < Cn; ++ci) {
                    const float2 kb = s_rd[ci];
                    if (fmaf(xp[(size_t)ci * HWn], kb.x, kb.y) > 0.f) b |= 1ull << ci;
                }
            }
            s_a[r][side ? (COLS - 1) : 0] = b;
        }
    }
    __syncthreads();

    // -------- phase 2: co-quad loop; A re-read per quad via contiguous b128 ---
    const int r   = tid >> 5;             // 0..7
    const int c0  = (tid & 31) * 2;       // 0..62 (2 pixels/thread)
    const int gw0 = w0 + c0;
    const int h   = h0 + r;
    const int htop = (h == 0), hbot = (h == Hn - 1);
    const int wl = (gw0 == 0), wr = (gw0 + 1 == Wn - 1);
    const int need = htop | hbot | wl | wr;

    const float* xp = x   + (size_t)n * Cn * HWn + (size_t)h * Wn + gw0;
    float*       op = out + (size_t)n * Cn * HWn + (size_t)h * Wn + gw0;

    const u64* ap = &s_a[r][c0];          // 16B-aligned (c0 even)
    for (int co0 = 0; co0 < Cn; co0 += 4) {
        // opaque pointer: blocks cross-iteration CSE/hoist of the A loads
        asm volatile("" : "+v"(ap));
        u64 A[3][4];
        #pragma unroll
        for (int dh = 0; dh < 3; ++dh) {
            const u64x2 t0 = *reinterpret_cast<const u64x2*>(ap + dh * COLS);
            const u64x2 t1 = *reinterpret_cast<const u64x2*>(ap + dh * COLS + 2);
            A[dh][0] = t0.x; A[dh][1] = t0.y; A[dh][2] = t1.x; A[dh][3] = t1.y;
        }
        // prefetch the quad's residuals so they fly during popcounts
        f32x2 xq[4];
        #pragma unroll
        for (int j = 0; j < 4; ++j)
            xq[j] = *reinterpret_cast<const f32x2*>(xp + (size_t)(co0 + j) * HWn);

        #pragma unroll
        for (int j = 0; j < 4; ++j) {
            const int co = co0 + j;
            const u64* wb = wbits + co * 9;     // uniform -> SGPR s_loads
            int a0 = 0, a1 = 0;
            #pragma unroll
            for (int dh = 0; dh < 3; ++dh) {
                const u64 q0 = wb[dh * 3], q1 = wb[dh * 3 + 1], q2 = wb[dh * 3 + 2];
                a0 += (int)__popcll(A[dh][0] ^ q0) + (int)__popcll(A[dh][1] ^ q1)
                    + (int)__popcll(A[dh][2] ^ q2);
                a1 += (int)__popcll(A[dh][1] ^ q0) + (int)__popcll(A[dh][2] ^ q1)
                    + (int)__popcll(A[dh][3] ^ q2);
            }
            int is0 = 576 - 2 * a0, is1 = 576 - 2 * a1;

            if (need) {
                const int* cx = corrx + co * 8;
                const int sb = (htop ? cx[0] : 0) + (hbot ? cx[1] : 0);
                is0 -= sb; is1 -= sb;
                if (wl) is0 -= cx[2] - (htop ? cx[4] : 0) - (hbot ? cx[6] : 0);
                if (wr) is1 -= cx[3] - (htop ? cx[5] : 0) - (hbot ? cx[7] : 0);
            }

            const float4 p4 = par[co];          // uniform -> s_load
            float y0 = fmaf(p4.x, (float)is0, p4.y);
            y0 = (y0 >= 0.f) ? y0 : y0 * p4.z;
            float y1 = fmaf(p4.x, (float)is1, p4.y);
            y1 = (y1 >= 0.f) ? y1 : y1 * p4.z;
            f32x2 o = { y0 + p4.w + xq[j].x, y1 + p4.w + xq[j].y };
            __builtin_nontemporal_store(o, reinterpret_cast<f32x2*>(op + (size_t)co * HWn));
        }
    }
}

// ---------------- host launcher ----------------
extern "C" void kernel_launch(void* const* d_in, const int* in_sizes, int n_in,
                              void* d_out, int out_size, void* d_ws, size_t ws_size,
                              hipStream_t stream) {
    const float* x      = (const float*)d_in[0];
    const float* rd_k   = (const float*)d_in[1];
    const float* rd_b   = (const float*)d_in[2];
    // d_in[3] = beta: unused in forward (STE forward = hard sign)
    const float* conv_w = (const float*)d_in[4];
    const float* pb0    = (const float*)d_in[5];
    const float* pw     = (const float*)d_in[6];
    const float* pb1    = (const float*)d_in[7];
    float* out = (float*)d_out;

    uint8_t* ws = (uint8_t*)d_ws;
    u64*    wbits = (u64*)ws;                    // 4608 B
    float4* par   = (float4*)(ws + 4608);        // 1024 B
    int*    corrx = (int*)(ws + 4608 + 1024);    // 2048 B

    pack_weights<<<Cn, 64, 0, stream>>>(conv_w, pb0, pw, pb1, wbits, par, corrx);
    fused<<<NBLK, 256, 0, stream>>>(x, rd_k, rd_b, wbits, par, corrx, out);
}

// Round 12
// 160.200 us; speedup vs baseline: 1.2781x; 1.2781x over previous
//
#include <hip/hip_runtime.h>
#include <cstdint>
#include <cstddef>

#define Bn 16
#define Cn 64
#define Hn 256
#define Wn 256
#define HWn (Hn * Wn)          // 65536
#define TH 8                   // tile rows (full image width)
#define ROWS (TH + 2)          // 10
#define COLS (Wn + 2)          // 258
#define NBLK (Bn * (Hn / TH))  // 512
#define THREADS 512

typedef unsigned long long u64;
typedef u64   u64x2 __attribute__((ext_vector_type(2)));
typedef float f32x4 __attribute__((ext_vector_type(4)));

// ---- kernel C: weight sign bits + per-co params + edge-corr sums -------------
__global__ __launch_bounds__(64) void pack_weights(const float* __restrict__ w,
                                                   const float* __restrict__ b0g,
                                                   const float* __restrict__ pwg,
                                                   const float* __restrict__ b1g,
                                                   u64* __restrict__ wbits,
                                                   float4* __restrict__ par,
                                                   int* __restrict__ corrx) {
    const int co = blockIdx.x;
    const int ci = threadIdx.x;
    const float* wp = w + ((size_t)co * Cn + ci) * 9;
    float v[9];
    float asum = 0.f;
    #pragma unroll
    for (int t = 0; t < 9; ++t) { v[t] = wp[t]; asum += fabsf(v[t]); }
    u64 m[9];
    #pragma unroll
    for (int t = 0; t < 9; ++t) m[t] = __ballot(v[t] > 0.f);
    #pragma unroll
    for (int off = 32; off; off >>= 1) asum += __shfl_xor(asum, off);
    if (ci == 0) {
        int c[9];
        #pragma unroll
        for (int t = 0; t < 9; ++t) {
            wbits[co * 9 + t] = m[t];
            c[t] = 64 - 2 * (int)__popcll(m[t]);
        }
        int* cx = corrx + co * 8;
        cx[0] = c[0] + c[1] + c[2];   // top row pad
        cx[1] = c[6] + c[7] + c[8];   // bottom row pad
        cx[2] = c[0] + c[3] + c[6];   // left col pad
        cx[3] = c[2] + c[5] + c[8];   // right col pad
        cx[4] = c[0]; cx[5] = c[2];   // corner overlaps
        cx[6] = c[6]; cx[7] = c[8];
        par[co] = make_float4(asum * (1.f / (Cn * 9)), b0g[co], pwg[co], b1g[co]);
    }
}

// ---- fused kernel: pack 10x258 bit strip in LDS + co-quad reg-blocked conv ----
__global__ __launch_bounds__(THREADS, 4) void fused(const float* __restrict__ x,
                                                    const float* __restrict__ rdk,
                                                    const float* __restrict__ rdb,
                                                    const u64* __restrict__ wbits,
                                                    const float4* __restrict__ par,
                                                    const int* __restrict__ corrx,
                                                    float* __restrict__ out) {
    __shared__ __align__(16) u64 s_a[ROWS][COLS];   // 20640 B, zero pad cols
    __shared__ float2 s_rd[Cn];

    const int tid = threadIdx.x;
    // XCD-chunked bijective swizzle (512 % 8 == 0): each XCD owns 2 images.
    const int bid     = blockIdx.x;
    const int logical = (bid & 7) * (NBLK / 8) + (bid >> 3);
    const int n  = logical >> 5;
    const int h0 = (logical & 31) * TH;

    if (tid < Cn) s_rd[tid] = make_float2(rdk[tid], rdb[tid]);
    if (tid < 2 * ROWS) s_a[tid >> 1][(tid & 1) ? (COLS - 1) : 0] = 0;  // pad cols
    __syncthreads();

    // -------- phase 1: binarize+pack rows h0-1..h0+8, full width (f32x4) ------
    const float* xn = x + (size_t)n * Cn * HWn;
    for (int task = tid; task < 640; task += THREADS) {   // 10 rows x 64 quads
        const int r  = task >> 6;
        const int q  = task & 63;
        const int gh = h0 - 1 + r;
        const int gw = 4 * q;
        u64 b0 = 0, b1 = 0, b2 = 0, b3 = 0;
        if (gh >= 0 && gh < Hn) {
            const float* xp = xn + (size_t)gh * Wn + gw;
            #pragma unroll 8
            for (int ci = 0; ci < Cn; ++ci) {
                const float2 kb = s_rd[ci];
                const f32x4 v = *reinterpret_cast<const f32x4*>(xp + (size_t)ci * HWn);
                const u64 bit = 1ull << ci;
                if (fmaf(v.x, kb.x, kb.y) > 0.f) b0 |= bit;
                if (fmaf(v.y, kb.x, kb.y) > 0.f) b1 |= bit;
                if (fmaf(v.z, kb.x, kb.y) > 0.f) b2 |= bit;
                if (fmaf(v.w, kb.x, kb.y) > 0.f) b3 |= bit;
            }
        }
        s_a[r][1 + gw] = b0;
        s_a[r][2 + gw] = b1;
        s_a[r][3 + gw] = b2;
        s_a[r][4 + gw] = b3;
    }
    __syncthreads();

    // -------- phase 2: co-quad loop, A-window re-read per quad (b128) ---------
    const int r  = tid >> 6;            // 0..7
    const int c0 = (tid & 63) * 4;      // 0..252 (4 px/thread)
    const int h  = h0 + r;
    const int htop = (h == 0), hbot = (h == Hn - 1);
    const int wl = (c0 == 0), wr = (c0 + 3 == Wn - 1);
    const int need = htop | hbot | wl | wr;

    const float* xp = x   + (size_t)n * Cn * HWn + (size_t)h * Wn + c0;
    float*       op = out + (size_t)n * Cn * HWn + (size_t)h * Wn + c0;

    const u64* ap = &s_a[r][c0];        // 16B-aligned (c0 even)
    for (int co0 = 0; co0 < Cn; co0 += 4) {
        // opaque pointer: blocks cross-quad CSE/hoist of the A loads
        asm volatile("" : "+v"(ap));
        u64 A[3][6];
        #pragma unroll
        for (int dh = 0; dh < 3; ++dh) {
            const u64x2 t0 = *reinterpret_cast<const u64x2*>(ap + dh * COLS);
            const u64x2 t1 = *reinterpret_cast<const u64x2*>(ap + dh * COLS + 2);
            const u64x2 t2 = *reinterpret_cast<const u64x2*>(ap + dh * COLS + 4);
            A[dh][0] = t0.x; A[dh][1] = t0.y; A[dh][2] = t1.x;
            A[dh][3] = t1.y; A[dh][4] = t2.x; A[dh][5] = t2.y;
        }
        // per-quad value pin: forbids within-quad remat; lifetime is only this
        // iteration (36 VGPRs transient), unlike the refused whole-loop pins.
        #pragma unroll
        for (int dh = 0; dh < 3; ++dh)
            #pragma unroll
            for (int j = 0; j < 6; ++j)
                asm volatile("" : "+v"(A[dh][j]));

        // prefetch the quad's residuals so they fly during popcounts
        f32x4 xq[4];
        #pragma unroll
        for (int j = 0; j < 4; ++j)
            xq[j] = *reinterpret_cast<const f32x4*>(xp + (size_t)(co0 + j) * HWn);

        #pragma unroll
        for (int j = 0; j < 4; ++j) {
            const int co = co0 + j;
            const u64* wb = wbits + co * 9;     // uniform -> SGPR s_loads
            int is[4];
            #pragma unroll
            for (int p = 0; p < 4; ++p) {
                int acc = 0;
                #pragma unroll
                for (int dh = 0; dh < 3; ++dh) {
                    acc += (int)__popcll(A[dh][p]     ^ wb[dh * 3]);
                    acc += (int)__popcll(A[dh][p + 1] ^ wb[dh * 3 + 1]);
                    acc += (int)__popcll(A[dh][p + 2] ^ wb[dh * 3 + 2]);
                }
                is[p] = 576 - 2 * acc;
            }

            if (need) {
                const int* cx = corrx + co * 8;
                const int sb = (htop ? cx[0] : 0) + (hbot ? cx[1] : 0);
                #pragma unroll
                for (int p = 0; p < 4; ++p) is[p] -= sb;
                if (wl) is[0] -= cx[2] - (htop ? cx[4] : 0) - (hbot ? cx[6] : 0);
                if (wr) is[3] -= cx[3] - (htop ? cx[5] : 0) - (hbot ? cx[7] : 0);
            }

            const float4 p4 = par[co];          // uniform -> s_load
            f32x4 o;
            #pragma unroll
            for (int p = 0; p < 4; ++p) {
                float y = fmaf(p4.x, (float)is[p], p4.y);
                y = (y >= 0.f) ? y : y * p4.z;
                o[p] = y + p4.w + xq[j][p];
            }
            __builtin_nontemporal_store(o, reinterpret_cast<f32x4*>(op + (size_t)co * HWn));
        }
    }
}

// ---------------- host launcher ----------------
extern "C" void kernel_launch(void* const* d_in, const int* in_sizes, int n_in,
                              void* d_out, int out_size, void* d_ws, size_t ws_size,
                              hipStream_t stream) {
    const float* x      = (const float*)d_in[0];
    const float* rd_k   = (const float*)d_in[1];
    const float* rd_b   = (const float*)d_in[2];
    // d_in[3] = beta: unused in forward (STE forward = hard sign)
    const float* conv_w = (const float*)d_in[4];
    const float* pb0    = (const float*)d_in[5];
    const float* pw     = (const float*)d_in[6];
    const float* pb1    = (const float*)d_in[7];
    float* out = (float*)d_out;

    uint8_t* ws = (uint8_t*)d_ws;
    u64*    wbits = (u64*)ws;                    // 4608 B
    float4* par   = (float4*)(ws + 4608);        // 1024 B
    int*    corrx = (int*)(ws + 4608 + 1024);    // 2048 B

    pack_weights<<<Cn, 64, 0, stream>>>(conv_w, pb0, pw, pb1, wbits, par, corrx);
    fused<<<NBLK, THREADS, 0, stream>>>(x, rd_k, rd_b, wbits, par, corrx, out);
}